// Round 1
// baseline (985.006 us; speedup 1.0000x reference)
//
#include <hip/hip_runtime.h>
#include <math.h>

#define B_    4
#define T_    2048
#define DIN   1024
#define DKV   64
#define QROWS 16

// ---------------- fused Q/K/V projection ----------------
// grid: 8192/32 = 256 blocks, 256 threads.
// Each block computes 32 token-rows x 64 cols for Q, K, V (x staged once in LDS).
__global__ __launch_bounds__(256) void proj_kernel(
    const float* __restrict__ x,
    const float* __restrict__ Wq,
    const float* __restrict__ Wk,
    const float* __restrict__ Wv,
    float* __restrict__ Qo,
    float* __restrict__ Ko,
    float* __restrict__ Vo)
{
    __shared__ float xs[32][64];
    const int row0 = blockIdx.x * 32;
    const int t  = threadIdx.x;
    const int tx = t & 15;   // cols 4*tx .. 4*tx+3
    const int ty = t >> 4;   // rows 2*ty, 2*ty+1

    float acc[3][2][4];
#pragma unroll
    for (int w = 0; w < 3; ++w)
#pragma unroll
        for (int j = 0; j < 2; ++j)
#pragma unroll
            for (int c = 0; c < 4; ++c) acc[w][j][c] = 0.f;

    const float* Wl[3] = {Wq, Wk, Wv};

    for (int k0 = 0; k0 < DIN; k0 += 64) {
        // stage x tile [32][64]; 2048 floats / 256 thr = 8 each (two float4)
        {
            const int idx = t * 8;
            const int r = idx >> 6;
            const int c = idx & 63;
            const float* src = x + (size_t)(row0 + r) * DIN + k0 + c;
            *(float4*)&xs[r][c]     = *(const float4*)(src);
            *(float4*)&xs[r][c + 4] = *(const float4*)(src + 4);
        }
        __syncthreads();
#pragma unroll 8
        for (int kk = 0; kk < 64; ++kk) {
            const float x0 = xs[2 * ty][kk];
            const float x1 = xs[2 * ty + 1][kk];
#pragma unroll
            for (int w = 0; w < 3; ++w) {
                const float4 wv = *(const float4*)(Wl[w] + (size_t)(k0 + kk) * DKV + 4 * tx);
                acc[w][0][0] += x0 * wv.x; acc[w][0][1] += x0 * wv.y;
                acc[w][0][2] += x0 * wv.z; acc[w][0][3] += x0 * wv.w;
                acc[w][1][0] += x1 * wv.x; acc[w][1][1] += x1 * wv.y;
                acc[w][1][2] += x1 * wv.z; acc[w][1][3] += x1 * wv.w;
            }
        }
        __syncthreads();
    }

    float* Out[3] = {Qo, Ko, Vo};
#pragma unroll
    for (int w = 0; w < 3; ++w)
#pragma unroll
        for (int j = 0; j < 2; ++j) {
            float4 v4 = make_float4(acc[w][j][0], acc[w][j][1], acc[w][j][2], acc[w][j][3]);
            *(float4*)(Out[w] + (size_t)(row0 + 2 * ty + j) * DKV + 4 * tx) = v4;
        }
}

// ---------------- flash-style causal attention ----------------
// grid: (T/QROWS, B), block 256 = 4 waves; each wave owns 4 query rows.
// Per key-tile of 64: lane = key within tile for scores; lane = head-dim for PV.
__global__ __launch_bounds__(256) void attn_kernel(
    const float* __restrict__ Q,
    const float* __restrict__ K,
    const float* __restrict__ V,
    float* __restrict__ out)
{
    __shared__ float Ks[64][65];   // stride 65: (lane+d)%32 banks -> 2-way (free)
    __shared__ float Vs[64][65];
    __shared__ float qs[QROWS][64];
    __shared__ float ps[4][4][64]; // [wave][row][key]

    const int b    = blockIdx.y;
    const int q0   = blockIdx.x * QROWS;
    const int t    = threadIdx.x;
    const int wave = t >> 6;
    const int lane = t & 63;

    const float* Qb = Q + (size_t)b * T_ * DKV;
    const float* Kb = K + (size_t)b * T_ * DKV;
    const float* Vb = V + (size_t)b * T_ * DKV;

    // stage Q rows for this block: 1024 floats / 256 thr = 4 each
    {
        const int idx = t * 4;
        const int r = idx >> 6;
        const int c = idx & 63;
        *(float4*)&qs[r][c] = *(const float4*)(Qb + (size_t)(q0 + r) * DKV + c);
    }

    float m[4], ssum[4], acc[4];
#pragma unroll
    for (int i = 0; i < 4; ++i) { m[i] = -INFINITY; ssum[i] = 0.f; acc[i] = 0.f; }

    const int rbase = q0 + wave * 4;
    const int nt = (q0 + QROWS + 63) >> 6;   // key tiles covering 0 .. q0+QROWS-1

    for (int tile = 0; tile < nt; ++tile) {
        const int j0 = tile * 64;
        __syncthreads();   // previous tile's Vs/ps reads complete before overwrite
        // stage K,V tiles: each thread loads 16 floats of each (row t/4, quarter-row)
        {
            const int r  = t >> 2;
            const int c0 = (t & 3) * 16;
            const float* ksrc = Kb + (size_t)(j0 + r) * DKV + c0;
            const float* vsrc = Vb + (size_t)(j0 + r) * DKV + c0;
#pragma unroll
            for (int u = 0; u < 16; u += 4) {
                const float4 kv = *(const float4*)(ksrc + u);
                const float4 vv = *(const float4*)(vsrc + u);
                Ks[r][c0 + u] = kv.x; Ks[r][c0 + u + 1] = kv.y;
                Ks[r][c0 + u + 2] = kv.z; Ks[r][c0 + u + 3] = kv.w;
                Vs[r][c0 + u] = vv.x; Vs[r][c0 + u + 1] = vv.y;
                Vs[r][c0 + u + 2] = vv.z; Vs[r][c0 + u + 3] = vv.w;
            }
        }
        __syncthreads();

        // scores + online softmax, one row at a time (lane = key j0+lane)
#pragma unroll
        for (int i = 0; i < 4; ++i) {
            const int r = rbase + i;
            float s = 0.f;
#pragma unroll 16
            for (int d = 0; d < 64; ++d)
                s += qs[wave * 4 + i][d] * Ks[lane][d];
            const bool valid = (j0 + lane) <= r;
            s = valid ? s : -INFINITY;
            float tmax = s;
#pragma unroll
            for (int msk = 32; msk; msk >>= 1) tmax = fmaxf(tmax, __shfl_xor(tmax, msk, 64));
            const float mnew = fmaxf(m[i], tmax);
            const float p = valid ? __expf(s - mnew) : 0.f;
            float psum = p;
#pragma unroll
            for (int msk = 32; msk; msk >>= 1) psum += __shfl_xor(psum, msk, 64);
            const float corr = __expf(m[i] - mnew);   // 0 when m was -inf
            ssum[i] = ssum[i] * corr + psum;
            acc[i] *= corr;
            m[i] = mnew;
            ps[wave][i][lane] = p;
        }
        __syncthreads();   // ps visible

        // PV: lane = head dim
#pragma unroll
        for (int i = 0; i < 4; ++i) {
            float a = acc[i];
#pragma unroll 16
            for (int k = 0; k < 64; ++k)
                a += ps[wave][i][k] * Vs[k][lane];
            acc[i] = a;
        }
    }

    float* ob = out + ((size_t)b * T_ + rbase) * DKV;
#pragma unroll
    for (int i = 0; i < 4; ++i)
        ob[(size_t)i * DKV + lane] = acc[i] / ssum[i] * 0.125f;
}

extern "C" void kernel_launch(void* const* d_in, const int* in_sizes, int n_in,
                              void* d_out, int out_size, void* d_ws, size_t ws_size,
                              hipStream_t stream) {
    const float* x  = (const float*)d_in[0];
    const float* Wq = (const float*)d_in[1];
    const float* Wk = (const float*)d_in[2];
    const float* Wv = (const float*)d_in[3];
    float* out = (float*)d_out;

    float* Qbuf = (float*)d_ws;                       // [8192][64]
    float* Kbuf = Qbuf + (size_t)B_ * T_ * DKV;       // [8192][64]
    float* Vbuf = Kbuf + (size_t)B_ * T_ * DKV;       // [8192][64]

    proj_kernel<<<dim3((B_ * T_) / 32), dim3(256), 0, stream>>>(x, Wq, Wk, Wv, Qbuf, Kbuf, Vbuf);

    dim3 grid(T_ / QROWS, B_);
    attn_kernel<<<grid, dim3(256), 0, stream>>>(Qbuf, Kbuf, Vbuf, out);
}

// Round 2
// 285.003 us; speedup vs baseline: 3.4561x; 3.4561x over previous
//
#include <hip/hip_runtime.h>
#include <math.h>

#define B_    4
#define T_    2048
#define DIN   1024
#define DKV   64
#define KC    32     // K-chunk for proj
#define MT    32     // M-tile rows for proj
#define QROWS 16
#define PAD   68     // LDS row pad (floats): stride 68 => conflict-free b128 row reads

typedef const __attribute__((address_space(1))) unsigned GU;
typedef __attribute__((address_space(3))) unsigned LU;

__device__ __forceinline__ void gl_lds16(const void* g, void* l) {
    // dest = wave-uniform LDS base + lane*16 ; src = per-lane global address
    __builtin_amdgcn_global_load_lds((GU*)g, (LU*)l, 16, 0, 0);
}

// ---------------- fused Q/K/V projection: [8192x1024] @ [1024x192] ----------------
// 256 blocks x 512 threads. M-tile 32, double-buffered LDS (x tile + all 3 W chunks).
__global__ __launch_bounds__(512) void proj_kernel(
    const float* __restrict__ x,
    const float* __restrict__ Wq,
    const float* __restrict__ Wk,
    const float* __restrict__ Wv,
    float* __restrict__ Qo,
    float* __restrict__ Ko,
    float* __restrict__ Vo)
{
    __shared__ float Ws[2][3][KC][64];   // 48 KB : W chunk, exact global layout per array
    __shared__ float xs[2][MT][KC];      //  8 KB : x tile, linear (gl_lds-compatible)

    const int t    = threadIdx.x;
    const int wave = t >> 6;
    const int lane = t & 63;
    const int tx   = t & 15;   // 4-col group
    const int ty   = t >> 4;   // row 0..31
    const int row0 = blockIdx.x * MT;

    const float* Wl[3] = {Wq, Wk, Wv};

    float acc[3][4];
#pragma unroll
    for (int w = 0; w < 3; ++w)
#pragma unroll
        for (int c = 0; c < 4; ++c) acc[w][c] = 0.f;

    auto stage = [&](int buf, int ch) {
        const int k0 = ch * KC;
        // W chunks: 3 x 8KB contiguous in global; 24KB split as 3KB per wave
#pragma unroll
        for (int j = 0; j < 3; ++j) {
            const int off  = wave * 3072 + j * 1024;   // byte offset in 24KB region
            const int a    = off >> 13;                // which W array (8KB each)
            const int aoff = off & 8191;
            const char* src = (const char*)Wl[a] + (size_t)k0 * 64 * 4 + aoff + (size_t)lane * 16;
            char* dst = (char*)&Ws[buf][0][0][0] + off;
            gl_lds16(src, dst);
        }
        // x tile: 32 rows x 32 cols = 4KB; waves 0..3 stage 1KB each
        if (wave < 4) {
            const int r = wave * 8 + (lane >> 3);
            const int c = (lane & 7) * 4;
            const float* src = x + (size_t)(row0 + r) * DIN + k0 + c;
            char* dst = (char*)&xs[buf][0][0] + wave * 1024;
            gl_lds16(src, dst);
        }
    };

    auto compute = [&](int buf) {
#pragma unroll
        for (int g = 0; g < KC / 4; ++g) {
            const float4 xv = *(const float4*)&xs[buf][ty][g * 4];
#pragma unroll
            for (int u = 0; u < 4; ++u) {
                const float xu = (&xv.x)[u];
#pragma unroll
                for (int w = 0; w < 3; ++w) {
                    const float4 wv = *(const float4*)&Ws[buf][w][g * 4 + u][tx * 4];
                    acc[w][0] += xu * wv.x; acc[w][1] += xu * wv.y;
                    acc[w][2] += xu * wv.z; acc[w][3] += xu * wv.w;
                }
            }
        }
    };

    stage(0, 0);
    __syncthreads();          // waits vmcnt(0) + barrier
    int buf = 0;
    const int NCH = DIN / KC; // 32
    for (int ch = 0; ch < NCH; ++ch) {
        if (ch + 1 < NCH) stage(buf ^ 1, ch + 1);   // issue next-chunk loads
        compute(buf);                               // overlap with loads in flight
        __syncthreads();                            // drain vmcnt + barrier
        buf ^= 1;
    }

    float* Out[3] = {Qo, Ko, Vo};
#pragma unroll
    for (int w = 0; w < 3; ++w) {
        const float4 v4 = make_float4(acc[w][0], acc[w][1], acc[w][2], acc[w][3]);
        *(float4*)(Out[w] + (size_t)(row0 + ty) * DKV + tx * 4) = v4;
    }
}

// ---------------- flash-style causal attention ----------------
// grid (T/QROWS, B), reversed x order (big blocks first). 256 thr = 4 waves x 4 q-rows.
__global__ __launch_bounds__(256) void attn_kernel(
    const float* __restrict__ Q,
    const float* __restrict__ K,
    const float* __restrict__ V,
    float* __restrict__ out)
{
    __shared__ float Ks[64][PAD];       // K tile, row-major
    __shared__ float Vt[64][PAD];       // V tile TRANSPOSED: Vt[dim][key]
    __shared__ float qs[QROWS][PAD];
    __shared__ float ps[4][4][PAD];     // per-wave P rows

    const int b    = blockIdx.y;
    const int q0   = (gridDim.x - 1 - blockIdx.x) * QROWS;
    const int t    = threadIdx.x;
    const int wave = t >> 6;
    const int lane = t & 63;

    const float* Qb = Q + (size_t)b * T_ * DKV;
    const float* Kb = K + (size_t)b * T_ * DKV;
    const float* Vb = V + (size_t)b * T_ * DKV;

    {   // stage Q rows (16 x 64)
        const int r = t >> 4;
        const int c = (t & 15) * 4;
        *(float4*)&qs[r][c] = *(const float4*)(Qb + (size_t)(q0 + r) * DKV + c);
    }

    float m[4], ssum[4], acc[4];
#pragma unroll
    for (int i = 0; i < 4; ++i) { m[i] = -INFINITY; ssum[i] = 0.f; acc[i] = 0.f; }

    const int rbase = q0 + wave * 4;
    const int nt = (q0 + QROWS + 63) >> 6;

    for (int tile = 0; tile < nt; ++tile) {
        const int j0 = tile * 64;
        __syncthreads();   // previous tile fully consumed before overwrite
        {   // stage K row-major + V transposed
            const int r  = t >> 2;
            const int c0 = (t & 3) * 16;
            const float* ksrc = Kb + (size_t)(j0 + r) * DKV + c0;
            const float* vsrc = Vb + (size_t)(j0 + r) * DKV + c0;
#pragma unroll
            for (int u = 0; u < 16; u += 4) {
                const float4 kv = *(const float4*)(ksrc + u);
                *(float4*)&Ks[r][c0 + u] = kv;
                const float4 vv = *(const float4*)(vsrc + u);
                Vt[c0 + u][r]     = vv.x;
                Vt[c0 + u + 1][r] = vv.y;
                Vt[c0 + u + 2][r] = vv.z;
                Vt[c0 + u + 3][r] = vv.w;
            }
        }
        __syncthreads();

        // scores: lane = key, K-row read reused across this wave's 4 q-rows
        float s[4] = {0.f, 0.f, 0.f, 0.f};
#pragma unroll
        for (int dg = 0; dg < 16; ++dg) {
            const float4 kv = *(const float4*)&Ks[lane][dg * 4];
#pragma unroll
            for (int i = 0; i < 4; ++i) {
                const float4 qv = *(const float4*)&qs[wave * 4 + i][dg * 4];  // broadcast
                s[i] += qv.x * kv.x + qv.y * kv.y + qv.z * kv.z + qv.w * kv.w;
            }
        }

        // online softmax per row
#pragma unroll
        for (int i = 0; i < 4; ++i) {
            const int r = rbase + i;
            const bool valid = (j0 + lane) <= r;
            float sv = valid ? s[i] : -INFINITY;
            float tmax = sv;
#pragma unroll
            for (int msk = 32; msk; msk >>= 1) tmax = fmaxf(tmax, __shfl_xor(tmax, msk, 64));
            const float mnew = fmaxf(m[i], tmax);
            const float p = valid ? __expf(sv - mnew) : 0.f;
            float psum = p;
#pragma unroll
            for (int msk = 32; msk; msk >>= 1) psum += __shfl_xor(psum, msk, 64);
            const float corr = __expf(m[i] - mnew);   // 0 when m was -inf
            ssum[i] = ssum[i] * corr + psum;
            acc[i] *= corr;
            m[i] = mnew;
            ps[wave][i][lane] = p;    // same-wave producer/consumer: no barrier needed
        }

        // PV: lane = dim; Vt row read reused across 4 q-rows, float4 over keys
#pragma unroll
        for (int kg = 0; kg < 16; ++kg) {
            const float4 vt4 = *(const float4*)&Vt[lane][kg * 4];
#pragma unroll
            for (int i = 0; i < 4; ++i) {
                const float4 pv = *(const float4*)&ps[wave][i][kg * 4];   // broadcast
                acc[i] += pv.x * vt4.x + pv.y * vt4.y + pv.z * vt4.z + pv.w * vt4.w;
            }
        }
    }

    float* ob = out + ((size_t)b * T_ + rbase) * DKV;
#pragma unroll
    for (int i = 0; i < 4; ++i)
        ob[(size_t)i * DKV + lane] = acc[i] / ssum[i] * 0.125f;
}

extern "C" void kernel_launch(void* const* d_in, const int* in_sizes, int n_in,
                              void* d_out, int out_size, void* d_ws, size_t ws_size,
                              hipStream_t stream) {
    const float* x  = (const float*)d_in[0];
    const float* Wq = (const float*)d_in[1];
    const float* Wk = (const float*)d_in[2];
    const float* Wv = (const float*)d_in[3];
    float* outp = (float*)d_out;

    float* Qbuf = (float*)d_ws;
    float* Kbuf = Qbuf + (size_t)B_ * T_ * DKV;
    float* Vbuf = Kbuf + (size_t)B_ * T_ * DKV;

    proj_kernel<<<dim3((B_ * T_) / MT), dim3(512), 0, stream>>>(x, Wq, Wk, Wv, Qbuf, Kbuf, Vbuf);

    dim3 grid(T_ / QROWS, B_);
    attn_kernel<<<grid, dim3(256), 0, stream>>>(Qbuf, Kbuf, Vbuf, outp);
}

// Round 4
// 124.875 us; speedup vs baseline: 7.8880x; 2.2823x over previous
//
#include <hip/hip_runtime.h>
#include <math.h>

typedef unsigned short u16;
typedef __attribute__((ext_vector_type(4))) float f32x4;
typedef __bf16 bf16x8 __attribute__((ext_vector_type(8)));

#define MFMA16(a,b,c) __builtin_amdgcn_mfma_f32_16x16x32_bf16((a),(b),(c),0,0,0)

__device__ __forceinline__ u16 f2b(float f) {
    __bf16 h = (__bf16)f;             // RNE
    return __builtin_bit_cast(u16, h);
}
__device__ __forceinline__ float b2f(u16 u) {
    unsigned v = (unsigned)u << 16;
    return __builtin_bit_cast(float, v);
}

// ---------- 1. W transpose + hi/lo split: W[1024][64] f32 x3 -> Wthi/Wtlo[192][1024] ----------
__global__ __launch_bounds__(256) void wtrans_kernel(
    const float* __restrict__ Wq, const float* __restrict__ Wk,
    const float* __restrict__ Wv, u16* __restrict__ Wthi, u16* __restrict__ Wtlo)
{
    const int row = blockIdx.x;                       // 0..191 (n index)
    const float* W = (row < 64) ? Wq : ((row < 128) ? Wk : Wv);
    const int n = row & 63;
    const int k = threadIdx.x * 4;
    u16 h[4], l[4];
#pragma unroll
    for (int i = 0; i < 4; ++i) {
        const float a = W[(size_t)(k + i) * 64 + n];
        h[i] = f2b(a);
        l[i] = f2b(a - b2f(h[i]));
    }
    uint2 vh, vl;
    vh.x = (unsigned)h[0] | ((unsigned)h[1] << 16);
    vh.y = (unsigned)h[2] | ((unsigned)h[3] << 16);
    vl.x = (unsigned)l[0] | ((unsigned)l[1] << 16);
    vl.y = (unsigned)l[2] | ((unsigned)l[3] << 16);
    *(uint2*)(Wthi + (size_t)row * 1024 + k) = vh;
    *(uint2*)(Wtlo + (size_t)row * 1024 + k) = vl;
}

// ---------- 2. fused QKV proj, split-precision MFMA ----------
// 512 blocks x 256 thr (4 waves). BM=16 token rows; wave w owns col-groups w*3..w*3+2.
// x staged hi/lo in LDS (issue-early/write-late); W fragments straight from L2-resident Wt.
__global__ __launch_bounds__(256) void proj_kernel(
    const float* __restrict__ x, const u16* __restrict__ Wthi, const u16* __restrict__ Wtlo,
    u16* __restrict__ Qhi, u16* __restrict__ Qlo,
    u16* __restrict__ Khi, u16* __restrict__ Klo, u16* __restrict__ Vt)
{
    __shared__ u16 XH[2][16 * 64];    // 2KB each buf, XOR-swizzled 16B slots
    __shared__ u16 XL[2][16 * 64];
    __shared__ u16 vs[16][72];        // V tile for transposed output

    const int t = threadIdx.x, w = t >> 6, lane = t & 63;
    const int lo = lane & 15, hi = lane >> 4;
    const int row0 = blockIdx.x * 16;

    f32x4 acc[3];
#pragma unroll
    for (int i = 0; i < 3; ++i) acc[i] = (f32x4){0.f, 0.f, 0.f, 0.f};

    float4 xr;
    const int xrr = t >> 4, xrc = (t & 15) * 4;            // this thread's x element
    const int xaddr = xrr * 64 + (((xrc >> 3) ^ (xrr & 7)) << 3) + (xrc & 7);

    auto issueX = [&](int k0) {
        xr = *(const float4*)(x + (size_t)(row0 + xrr) * 1024 + k0 + xrc);
    };
    auto writeX = [&](int buf) {
        u16 h0 = f2b(xr.x), h1 = f2b(xr.y), h2 = f2b(xr.z), h3 = f2b(xr.w);
        u16 l0 = f2b(xr.x - b2f(h0)), l1 = f2b(xr.y - b2f(h1));
        u16 l2 = f2b(xr.z - b2f(h2)), l3 = f2b(xr.w - b2f(h3));
        uint2 vh, vl;
        vh.x = (unsigned)h0 | ((unsigned)h1 << 16); vh.y = (unsigned)h2 | ((unsigned)h3 << 16);
        vl.x = (unsigned)l0 | ((unsigned)l1 << 16); vl.y = (unsigned)l2 | ((unsigned)l3 << 16);
        *(uint2*)&XH[buf][xaddr] = vh;
        *(uint2*)&XL[buf][xaddr] = vl;
    };

    issueX(0); writeX(0);
    __syncthreads();
    int buf = 0;
    for (int step = 0; step < 16; ++step) {
        if (step < 15) issueX((step + 1) * 64);
#pragma unroll
        for (int s = 0; s < 2; ++s) {
            const int ka = (((hi + 4 * s) ^ (lo & 7)) << 3);
            const bf16x8 ah = *(const bf16x8*)&XH[buf][lo * 64 + ka];
            const bf16x8 al = *(const bf16x8*)&XL[buf][lo * 64 + ka];
#pragma unroll
            for (int i = 0; i < 3; ++i) {
                const int cg = w * 3 + i;
                const size_t woff = (size_t)(cg * 16 + lo) * 1024 + step * 64 + s * 32 + hi * 8;
                const bf16x8 bh = *(const bf16x8*)(Wthi + woff);
                const bf16x8 bl = *(const bf16x8*)(Wtlo + woff);
                acc[i] = MFMA16(ah, bh, acc[i]);
                acc[i] = MFMA16(ah, bl, acc[i]);
                acc[i] = MFMA16(al, bh, acc[i]);
            }
        }
        if (step < 15) writeX(buf ^ 1);
        __syncthreads();
        buf ^= 1;
    }

    // epilogue: Q,K -> hi/lo global; V -> LDS tile then transposed global
#pragma unroll
    for (int i = 0; i < 3; ++i) {
        const int cg = w * 3 + i;
#pragma unroll
        for (int r = 0; r < 4; ++r) {
            const float v = acc[i][r];
            const int row = row0 + hi * 4 + r;
            const u16 h = f2b(v);
            if (cg < 4) {
                Qhi[(size_t)row * 64 + cg * 16 + lo] = h;
                Qlo[(size_t)row * 64 + cg * 16 + lo] = f2b(v - b2f(h));
            } else if (cg < 8) {
                Khi[(size_t)row * 64 + (cg - 4) * 16 + lo] = h;
                Klo[(size_t)row * 64 + (cg - 4) * 16 + lo] = f2b(v - b2f(h));
            } else {
                vs[hi * 4 + r][(cg - 8) * 16 + lo] = h;
            }
        }
    }
    __syncthreads();
    {   // Vt[b][d][tok] : 64 dims x 16 tokens, 256 threads -> 4 tokens each
        const int bb = row0 >> 11;
        const int tok0 = row0 & 2047;
        const int d = t >> 2, part = t & 3;
        u16 tmp[4];
#pragma unroll
        for (int i = 0; i < 4; ++i) tmp[i] = vs[part * 4 + i][d];
        uint2 v2;
        v2.x = (unsigned)tmp[0] | ((unsigned)tmp[1] << 16);
        v2.y = (unsigned)tmp[2] | ((unsigned)tmp[3] << 16);
        *(uint2*)(Vt + (size_t)bb * 131072 + (size_t)d * 2048 + tok0 + part * 4) = v2;
    }
}

// ---------- 3. flash attention, split-precision QK^T, bf16 PV ----------
// grid (128,4) x 64 thr (1 wave, 16 q-rows); causal-balanced pairing.
__global__ __launch_bounds__(64) void attn_kernel(
    const u16* __restrict__ Qhi, const u16* __restrict__ Qlo,
    const u16* __restrict__ Khi, const u16* __restrict__ Klo,
    const u16* __restrict__ Vt, float* __restrict__ out)
{
    __shared__ u16 P[16 * 64];   // per-wave P tile, XOR-swizzled

    const int bx = blockIdx.x, b = blockIdx.y;
    const int p = (bx & 1) ? (bx >> 1) : (127 - (bx >> 1));
    const int q0 = p * 16;
    const int l = threadIdx.x, lo = l & 15, hi = l >> 4;

    const u16* Qh = Qhi + (size_t)b * 131072;
    const u16* Ql = Qlo + (size_t)b * 131072;
    const u16* Kh = Khi + (size_t)b * 131072;
    const u16* Kl = Klo + (size_t)b * 131072;
    const u16* V  = Vt  + (size_t)b * 131072;

    bf16x8 aqh[2], aql[2];
#pragma unroll
    for (int s = 0; s < 2; ++s) {
        aqh[s] = *(const bf16x8*)(Qh + (size_t)(q0 + lo) * 64 + s * 32 + hi * 8);
        aql[s] = *(const bf16x8*)(Ql + (size_t)(q0 + lo) * 64 + s * 32 + hi * 8);
    }

    f32x4 acc[4];
    float m[4], ls[4];
#pragma unroll
    for (int r = 0; r < 4; ++r) { acc[r] = (f32x4){0.f,0.f,0.f,0.f}; m[r] = -INFINITY; ls[r] = 0.f; }

    const int ntiles = (q0 >> 6) + 1;
    for (int tile = 0; tile < ntiles; ++tile) {
        const int j0 = tile * 64;
        bf16x8 bkh[4][2], bkl[4][2], bv[4][2];
#pragma unroll
        for (int kg = 0; kg < 4; ++kg)
#pragma unroll
            for (int s = 0; s < 2; ++s) {
                const size_t off = (size_t)(j0 + kg * 16 + lo) * 64 + s * 32 + hi * 8;
                bkh[kg][s] = *(const bf16x8*)(Kh + off);
                bkl[kg][s] = *(const bf16x8*)(Kl + off);
            }
#pragma unroll
        for (int dg = 0; dg < 4; ++dg)
#pragma unroll
            for (int s = 0; s < 2; ++s)
                bv[dg][s] = *(const bf16x8*)(V + (size_t)(dg * 16 + lo) * 2048 + j0 + s * 32 + hi * 8);

        f32x4 S[4];
        const f32x4 zf = (f32x4){0.f,0.f,0.f,0.f};
#pragma unroll
        for (int kg = 0; kg < 4; ++kg) {
            f32x4 sv = zf;
            sv = MFMA16(aqh[0], bkh[kg][0], sv);
            sv = MFMA16(aqh[1], bkh[kg][1], sv);
            sv = MFMA16(aqh[0], bkl[kg][0], sv);
            sv = MFMA16(aqh[1], bkl[kg][1], sv);
            sv = MFMA16(aql[0], bkh[kg][0], sv);
            sv = MFMA16(aql[1], bkh[kg][1], sv);
            S[kg] = sv;
        }

        const bool dm = (tile == ntiles - 1);
#pragma unroll
        for (int r = 0; r < 4; ++r) {
            const int row = q0 + hi * 4 + r;
            float sv0 = S[0][r], sv1 = S[1][r], sv2 = S[2][r], sv3 = S[3][r];
            if (dm) {
                sv0 = (j0 +      lo > row) ? -INFINITY : sv0;
                sv1 = (j0 + 16 + lo > row) ? -INFINITY : sv1;
                sv2 = (j0 + 32 + lo > row) ? -INFINITY : sv2;
                sv3 = (j0 + 48 + lo > row) ? -INFINITY : sv3;
            }
            float mx = fmaxf(fmaxf(sv0, sv1), fmaxf(sv2, sv3));
#pragma unroll
            for (int msk = 8; msk; msk >>= 1) mx = fmaxf(mx, __shfl_xor(mx, msk, 64));
            const float mnew = fmaxf(m[r], mx);
            const u16 u0 = f2b(__expf(sv0 - mnew)), u1 = f2b(__expf(sv1 - mnew));
            const u16 u2 = f2b(__expf(sv2 - mnew)), u3 = f2b(__expf(sv3 - mnew));
            float ps = b2f(u0) + b2f(u1) + b2f(u2) + b2f(u3);   // sum the ROUNDED p
#pragma unroll
            for (int msk = 8; msk; msk >>= 1) ps += __shfl_xor(ps, msk, 64);
            const float corr = __expf(m[r] - mnew);
            ls[r] = ls[r] * corr + ps;
            m[r] = mnew;
#pragma unroll
            for (int dg = 0; dg < 4; ++dg) acc[dg][r] *= corr;
            const int rowL = hi * 4 + r;
            const int base = rowL * 64;
            const int sw = rowL & 7;
            P[base + (((0 + (lo >> 3)) ^ sw) << 3) + (lo & 7)] = u0;
            P[base + (((2 + (lo >> 3)) ^ sw) << 3) + (lo & 7)] = u1;
            P[base + (((4 + (lo >> 3)) ^ sw) << 3) + (lo & 7)] = u2;
            P[base + (((6 + (lo >> 3)) ^ sw) << 3) + (lo & 7)] = u3;
        }
        __syncthreads();   // 1-wave: cheap; orders P writes before cross-lane reads

        const bf16x8 pa0 = *(const bf16x8*)&P[lo * 64 + (((hi    ) ^ (lo & 7)) << 3)];
        const bf16x8 pa1 = *(const bf16x8*)&P[lo * 64 + (((hi + 4) ^ (lo & 7)) << 3)];
#pragma unroll
        for (int dg = 0; dg < 4; ++dg) {
            acc[dg] = MFMA16(pa0, bv[dg][0], acc[dg]);
            acc[dg] = MFMA16(pa1, bv[dg][1], acc[dg]);
        }
    }

#pragma unroll
    for (int dg = 0; dg < 4; ++dg)
#pragma unroll
        for (int r = 0; r < 4; ++r)
            out[((size_t)b * 2048 + q0 + hi * 4 + r) * 64 + dg * 16 + lo] = acc[dg][r] / ls[r] * 0.125f;
}

extern "C" void kernel_launch(void* const* d_in, const int* in_sizes, int n_in,
                              void* d_out, int out_size, void* d_ws, size_t ws_size,
                              hipStream_t stream) {
    const float* x  = (const float*)d_in[0];
    const float* Wq = (const float*)d_in[1];
    const float* Wk = (const float*)d_in[2];
    const float* Wv = (const float*)d_in[3];
    float* outp = (float*)d_out;

    u16* Wthi = (u16*)d_ws;              // 192*1024
    u16* Wtlo = Wthi + 196608;
    u16* Qhi  = Wtlo + 196608;           // 8192*64 each
    u16* Qlo  = Qhi + 524288;
    u16* Khi  = Qlo + 524288;
    u16* Klo  = Khi + 524288;
    u16* Vt   = Klo + 524288;            // [4][64][2048]

    wtrans_kernel<<<dim3(192), dim3(256), 0, stream>>>(Wq, Wk, Wv, Wthi, Wtlo);
    proj_kernel<<<dim3(512), dim3(256), 0, stream>>>(x, Wthi, Wtlo, Qhi, Qlo, Khi, Klo, Vt);
    attn_kernel<<<dim3(128, 4), dim3(64), 0, stream>>>(Qhi, Qlo, Khi, Klo, Vt, outp);
}